// Round 1
// baseline (597.697 us; speedup 1.0000x reference)
//
#include <hip/hip_runtime.h>

// Problem constants
#define BB 16
#define SS 8192
#define DD 512   // Q_DIM == K_DIM == ATTN_DIM

typedef float  f32x4  __attribute__((ext_vector_type(4)));
typedef __bf16 bf16x8 __attribute__((ext_vector_type(8)));
typedef __bf16 bf16x4 __attribute__((ext_vector_type(4)));

__device__ __forceinline__ void gload_lds16(const unsigned short* g, unsigned short* l) {
    __builtin_amdgcn_global_load_lds(
        (const __attribute__((address_space(1))) unsigned int*)(g),
        (__attribute__((address_space(3))) unsigned int*)(l), 16, 0, 0);
}

__device__ __forceinline__ void cvt_store_bf4(unsigned short* dst, f32x4 v) {
    bf16x4 o;
    o.x = (__bf16)v.x; o.y = (__bf16)v.y; o.z = (__bf16)v.z; o.w = (__bf16)v.w;
    *(bf16x4*)dst = o;   // 8-byte LDS store
}

__device__ __forceinline__ float tanh_fast(float x) {
    float e2 = __expf(2.0f * x);
    return 1.0f - 2.0f / (e2 + 1.0f);   // -> +/-1 correctly as e2 -> inf/0
}

// ---------------------------------------------------------------------------
// Kernel 1: qproj = query @ Wq  (fp32),  WkT[n][k] = bf16(Wk[k][n])
// ---------------------------------------------------------------------------
__global__ void prep_kernel(const float* __restrict__ query, const float* __restrict__ Wq,
                            const float* __restrict__ Wk, float* __restrict__ qproj,
                            unsigned short* __restrict__ WkT)
{
    const int bid = blockIdx.x, t = threadIdx.x;
    if (bid < DD) {                       // one block per output row n of WkT
        const int n = bid;
        for (int k = t; k < DD; k += 256) {
            __bf16 h = (__bf16)Wk[k * DD + n];
            WkT[n * DD + k] = __builtin_bit_cast(unsigned short, h);
        }
    } else {                              // blocks 512..527: qproj row b
        const int b = bid - DD;
        for (int n = t; n < DD; n += 256) {
            float acc = 0.0f;
            for (int k = 0; k < DD; ++k)
                acc = fmaf(query[b * DD + k], Wq[k * DD + n], acc);
            qproj[b * DD + n] = acc;
        }
    }
}

// ---------------------------------------------------------------------------
// Kernel 2: scores  e[b][s] = sum_n tanh(qproj[b][n] + (keys@Wk)[b][s][n]) * v[n]
// 64 s-rows per block, bf16 MFMA 16x16x32, K-chunks of 32 double-buffered.
// LDS tiles in MFMA-fragment-major layout: [tile][lane][8 bf16].
// ---------------------------------------------------------------------------
__global__ __launch_bounds__(256, 2) void score_kernel(
    const float* __restrict__ keys, const unsigned short* __restrict__ WkT,
    const float* __restrict__ qproj, const float* __restrict__ vvec,
    const int* __restrict__ mask, float* __restrict__ e_ws)
{
    __shared__ unsigned short ksA[2][4 * 512];    //  4 m-tiles * 512 shorts  (4 KB/buf)
    __shared__ unsigned short wtB[2][32 * 512];   // 32 n-tiles * 512 shorts (32 KB/buf)
    __shared__ float sm_part[4][64];

    const int tid  = threadIdx.x;
    const int w    = tid >> 6;        // wave 0..3 -> n slice [128w, 128w+128)
    const int lane = tid & 63;
    const int ml   = lane & 15;
    const int quad = lane >> 4;
    const int bid  = blockIdx.x;
    const int b    = bid >> 7;                 // 128 s-tiles per b
    const int s0   = (bid & 127) << 6;

    // keys staging: thread t covers row m = t>>2, float4 #(t&3) and #(t&3)+4 of each 32-k chunk
    const int m  = tid >> 2;
    const int q4 = tid & 3;
    const float* krow = keys + ((size_t)(b * SS + s0 + m)) * DD + q4 * 4;
    const int it  = m >> 4;
    const int g0  = q4 >> 1;
    const int j0  = (q4 & 1) * 4;
    const int stA0 = it * 512 + ((m & 15) + 16 * g0)       * 8 + j0;
    const int stA1 = it * 512 + ((m & 15) + 16 * (g0 + 2)) * 8 + j0;

    // WkT staging base for this lane: n = 128w + ml + 16r, k-group = quad
    const unsigned short* wg = WkT + (size_t)(w * 128 + ml) * DD + quad * 8;

    f32x4 acc[4][8];
#pragma unroll
    for (int i = 0; i < 4; ++i)
#pragma unroll
        for (int jn = 0; jn < 8; ++jn) acc[i][jn] = (f32x4){0.f, 0.f, 0.f, 0.f};

    // prologue: stage chunk 0 into buffer 0
#pragma unroll
    for (int r = 0; r < 8; ++r)
        gload_lds16(wg + (size_t)r * 16 * DD, &wtB[0][(w * 8 + r) * 512]);
    {
        f32x4 k0 = *(const f32x4*)(krow);
        f32x4 k1 = *(const f32x4*)(krow + 16);
        cvt_store_bf4(&ksA[0][stA0], k0);
        cvt_store_bf4(&ksA[0][stA1], k1);
    }
    __syncthreads();

    for (int j = 0; j < 16; ++j) {
        const int cur = j & 1;
        const int nxt = cur ^ 1;
        f32x4 k0, k1;
        if (j < 15) {
            const int kb = (j + 1) * 32;
#pragma unroll
            for (int r = 0; r < 8; ++r)
                gload_lds16(wg + kb + (size_t)r * 16 * DD, &wtB[nxt][(w * 8 + r) * 512]);
            k0 = *(const f32x4*)(krow + kb);
            k1 = *(const f32x4*)(krow + kb + 16);
        }
        bf16x8 af[4];
#pragma unroll
        for (int i = 0; i < 4; ++i)
            af[i] = *(const bf16x8*)&ksA[cur][i * 512 + lane * 8];
#pragma unroll
        for (int jn = 0; jn < 8; ++jn) {
            bf16x8 bfr = *(const bf16x8*)&wtB[cur][(w * 8 + jn) * 512 + lane * 8];
#pragma unroll
            for (int i = 0; i < 4; ++i)
                acc[i][jn] = __builtin_amdgcn_mfma_f32_16x16x32_bf16(af[i], bfr, acc[i][jn], 0, 0, 0);
        }
        if (j < 15) {
            cvt_store_bf4(&ksA[nxt][stA0], k0);
            cvt_store_bf4(&ksA[nxt][stA1], k1);
        }
        __syncthreads();
    }

    // epilogue: e-partials.  C layout: row = quad*4 + reg, col = ml
    float qv[8], vv[8];
#pragma unroll
    for (int jn = 0; jn < 8; ++jn) {
        const int n = w * 128 + jn * 16 + ml;
        qv[jn] = qproj[b * DD + n];
        vv[jn] = vvec[n];
    }
#pragma unroll
    for (int i = 0; i < 4; ++i) {
#pragma unroll
        for (int r = 0; r < 4; ++r) {
            float s = 0.0f;
#pragma unroll
            for (int jn = 0; jn < 8; ++jn) {
                float xx = acc[i][jn][r] + qv[jn];
                s += tanh_fast(xx) * vv[jn];
            }
            s += __shfl_xor(s, 1, 64);
            s += __shfl_xor(s, 2, 64);
            s += __shfl_xor(s, 4, 64);
            s += __shfl_xor(s, 8, 64);
            if (ml == 0) sm_part[w][i * 16 + quad * 4 + r] = s;
        }
    }
    __syncthreads();
    if (tid < 64) {
        float e = sm_part[0][tid] + sm_part[1][tid] + sm_part[2][tid] + sm_part[3][tid];
        const int mk = mask[b * SS + s0 + tid];
        e_ws[(size_t)b * SS + s0 + tid] = (mk == 0) ? -3.402823466e38f : e;
    }
}

// ---------------------------------------------------------------------------
// Kernel 3: row softmax of e -> a (d_out +8192), and zero c region (d_out)
// ---------------------------------------------------------------------------
__global__ void softmax_kernel(const float* __restrict__ e_ws, float* __restrict__ out)
{
    const int b = blockIdx.x, t = threadIdx.x;
    const int lane = t & 63, wv = t >> 6;      // 16 waves
    const float* row = e_ws + (size_t)b * SS;
    float x[8];
    float mx = -3.402823466e38f;
#pragma unroll
    for (int i = 0; i < 8; ++i) { x[i] = row[t + 1024 * i]; mx = fmaxf(mx, x[i]); }
#pragma unroll
    for (int off = 32; off >= 1; off >>= 1) mx = fmaxf(mx, __shfl_xor(mx, off, 64));
    __shared__ float rmax[16], rsum[16];
    if (lane == 0) rmax[wv] = mx;
    __syncthreads();
    float bm = rmax[0];
#pragma unroll
    for (int k = 1; k < 16; ++k) bm = fmaxf(bm, rmax[k]);
    float s = 0.0f, ev[8];
#pragma unroll
    for (int i = 0; i < 8; ++i) { ev[i] = __expf(x[i] - bm); s += ev[i]; }
#pragma unroll
    for (int off = 32; off >= 1; off >>= 1) s += __shfl_xor(s, off, 64);
    if (lane == 0) rsum[wv] = s;
    __syncthreads();
    float bs = 0.0f;
#pragma unroll
    for (int k = 0; k < 16; ++k) bs += rsum[k];
    const float inv = 1.0f / bs;
    float* arow = out + BB * DD + (size_t)b * SS;
#pragma unroll
    for (int i = 0; i < 8; ++i) arow[t + 1024 * i] = ev[i] * inv;
    if (t < DD) out[b * DD + t] = 0.0f;       // zero context accumulator
}

// ---------------------------------------------------------------------------
// Kernel 4: context c[b][k] += sum_s a[b][s] * keys[b][s][k]
// ---------------------------------------------------------------------------
__global__ __launch_bounds__(256) void context_kernel(
    const float* __restrict__ keys, const float* __restrict__ a, float* __restrict__ c)
{
    const int bid = blockIdx.x;
    const int b   = bid >> 5;                  // 32 chunks of 256 s each
    const int s0  = (bid & 31) << 8;
    const int t   = threadIdx.x;
    const int kk  = (t & 127) << 2;
    const int sh  = t >> 7;                    // waves 0,1: sh=0  waves 2,3: sh=1
    const float* ap = a + (size_t)b * SS + s0 + sh;
    const float* kp = keys + ((size_t)(b * SS + s0 + sh)) * DD + kk;
    f32x4 acc = {0.f, 0.f, 0.f, 0.f};
    for (int i = 0; i < 128; ++i) {
        float wgt = ap[2 * i];
        f32x4 kv  = *(const f32x4*)(kp + (size_t)(2 * i) * DD);
        acc.x += wgt * kv.x; acc.y += wgt * kv.y; acc.z += wgt * kv.z; acc.w += wgt * kv.w;
    }
    __shared__ f32x4 red[128];
    if (sh == 1) red[t & 127] = acc;
    __syncthreads();
    if (sh == 0) {
        f32x4 o = red[t];
        acc.x += o.x; acc.y += o.y; acc.z += o.z; acc.w += o.w;
        atomicAdd(&c[b * DD + kk + 0], acc.x);
        atomicAdd(&c[b * DD + kk + 1], acc.y);
        atomicAdd(&c[b * DD + kk + 2], acc.z);
        atomicAdd(&c[b * DD + kk + 3], acc.w);
    }
}

// ---------------------------------------------------------------------------
extern "C" void kernel_launch(void* const* d_in, const int* in_sizes, int n_in,
                              void* d_out, int out_size, void* d_ws, size_t ws_size,
                              hipStream_t stream)
{
    const float* query = (const float*)d_in[0];
    const float* keys  = (const float*)d_in[1];
    const int*   mask  = (const int*)  d_in[2];
    const float* Wq    = (const float*)d_in[3];
    const float* Wk    = (const float*)d_in[4];
    const float* v     = (const float*)d_in[5];
    float* out = (float*)d_out;

    // workspace layout
    float*          qproj = (float*)d_ws;                                   // 32 KB
    unsigned short* WkT   = (unsigned short*)((char*)d_ws + 32768);         // 512 KB
    float*          e_ws  = (float*)((char*)d_ws + 32768 + 524288);         // 512 KB

    prep_kernel   <<<DD + BB, 256, 0, stream>>>(query, Wq, Wk, qproj, WkT);
    score_kernel  <<<BB * (SS / 64), 256, 0, stream>>>(keys, WkT, qproj, v, mask, e_ws);
    softmax_kernel<<<BB, 1024, 0, stream>>>(e_ws, out);
    context_kernel<<<BB * (SS / 256), 256, 0, stream>>>(keys, out + BB * DD, out);
}

// Round 2
// 547.903 us; speedup vs baseline: 1.0909x; 1.0909x over previous
//
#include <hip/hip_runtime.h>

// Problem constants
#define BB 16
#define SS 8192
#define DD 512   // Q_DIM == K_DIM == ATTN_DIM

typedef float  f32x4  __attribute__((ext_vector_type(4)));
typedef __bf16 bf16x8 __attribute__((ext_vector_type(8)));
typedef __bf16 bf16x4 __attribute__((ext_vector_type(4)));

__device__ __forceinline__ void gload_lds16(const unsigned short* g, unsigned short* l) {
    __builtin_amdgcn_global_load_lds(
        (const __attribute__((address_space(1))) unsigned int*)(g),
        (__attribute__((address_space(3))) unsigned int*)(l), 16, 0, 0);
}

__device__ __forceinline__ void cvt_store_bf4(unsigned short* dst, f32x4 v) {
    bf16x4 o;
    o.x = (__bf16)v.x; o.y = (__bf16)v.y; o.z = (__bf16)v.z; o.w = (__bf16)v.w;
    *(bf16x4*)dst = o;   // 8-byte LDS store
}

__device__ __forceinline__ float tanh_fast(float x) {
    float e2 = __expf(2.0f * x);
    return 1.0f - 2.0f / (e2 + 1.0f);   // -> +/-1 correctly as e2 -> inf/0
}

// ---------------------------------------------------------------------------
// Kernel 1: qproj = query @ Wq  (fp32),  WkT[n][k] = bf16(Wk[k][n])
// ---------------------------------------------------------------------------
__global__ void prep_kernel(const float* __restrict__ query, const float* __restrict__ Wq,
                            const float* __restrict__ Wk, float* __restrict__ qproj,
                            unsigned short* __restrict__ WkT)
{
    const int bid = blockIdx.x, t = threadIdx.x;
    if (bid < DD) {                       // one block per output row n of WkT
        const int n = bid;
        for (int k = t; k < DD; k += 256) {
            __bf16 h = (__bf16)Wk[k * DD + n];
            WkT[n * DD + k] = __builtin_bit_cast(unsigned short, h);
        }
    } else {                              // blocks 512..543: qproj, one output/thread
        const int idx = (bid - DD) * 256 + t;   // 0..8191
        const int b = idx >> 9;
        const int n = idx & 511;
        const float* q  = query + b * DD;
        const float* wp = Wq + n;
        float acc = 0.0f;
#pragma unroll 8
        for (int k = 0; k < DD; ++k)
            acc = fmaf(q[k], wp[(size_t)k * DD], acc);
        qproj[b * DD + n] = acc;
    }
}

// ---------------------------------------------------------------------------
// Kernel 2 (fused): scores + block-local softmax stats + context partial.
//   e[b][s]   = sum_n tanh(qproj[b][n] + (keys@Wk)[b][s][n]) * v[n]  (masked)
//   m_blk     = max_s e, w_s = exp(e - m_blk), l_blk = sum w
//   cpart[n]  = sum_s w_s * keys[b][s][n]   (fp32 keys re-read, L2-hot)
// 64 s-rows per block, bf16 MFMA 16x16x32, K-chunks of 32 double-buffered.
// ---------------------------------------------------------------------------
__global__ __launch_bounds__(256, 2) void fused_kernel(
    const float* __restrict__ keys, const unsigned short* __restrict__ WkT,
    const float* __restrict__ qproj, const float* __restrict__ vvec,
    const int* __restrict__ mask, float* __restrict__ e_ws,
    float* __restrict__ cpart, float2* __restrict__ ml_ws)
{
    __shared__ unsigned short ksA[2][4 * 512];    //  4 m-tiles * 512 shorts  (4 KB/buf)
    __shared__ unsigned short wtB[2][32 * 512];   // 32 n-tiles * 512 shorts (32 KB/buf)
    __shared__ float sm_part[4][64];
    __shared__ float w_sh[64];
    __shared__ f32x4 red[128];

    const int tid  = threadIdx.x;
    const int w    = tid >> 6;        // wave 0..3 -> n slice [128w, 128w+128)
    const int lane = tid & 63;
    const int ml   = lane & 15;
    const int quad = lane >> 4;
    const int bid  = blockIdx.x;
    const int b    = bid >> 7;                 // 128 s-chunks per b
    const int chunk = bid & 127;
    const int s0   = chunk << 6;

    // keys staging: thread t covers row m = t>>2, float4 #(t&3) and #(t&3)+4 of each 32-k chunk
    const int m  = tid >> 2;
    const int q4 = tid & 3;
    const float* krow = keys + ((size_t)(b * SS + s0 + m)) * DD + q4 * 4;
    const int it  = m >> 4;
    const int g0  = q4 >> 1;
    const int j0  = (q4 & 1) * 4;
    const int stA0 = it * 512 + ((m & 15) + 16 * g0)       * 8 + j0;
    const int stA1 = it * 512 + ((m & 15) + 16 * (g0 + 2)) * 8 + j0;

    // WkT staging base for this lane: n = 128w + ml + 16r, k-group = quad
    const unsigned short* wg = WkT + (size_t)(w * 128 + ml) * DD + quad * 8;

    f32x4 acc[4][8];
#pragma unroll
    for (int i = 0; i < 4; ++i)
#pragma unroll
        for (int jn = 0; jn < 8; ++jn) acc[i][jn] = (f32x4){0.f, 0.f, 0.f, 0.f};

    // prologue: stage chunk 0 into buffer 0
#pragma unroll
    for (int r = 0; r < 8; ++r)
        gload_lds16(wg + (size_t)r * 16 * DD, &wtB[0][(w * 8 + r) * 512]);
    {
        f32x4 k0 = *(const f32x4*)(krow);
        f32x4 k1 = *(const f32x4*)(krow + 16);
        cvt_store_bf4(&ksA[0][stA0], k0);
        cvt_store_bf4(&ksA[0][stA1], k1);
    }
    __syncthreads();

    for (int j = 0; j < 16; ++j) {
        const int cur = j & 1;
        const int nxt = cur ^ 1;
        f32x4 k0, k1;
        if (j < 15) {
            const int kb = (j + 1) * 32;
#pragma unroll
            for (int r = 0; r < 8; ++r)
                gload_lds16(wg + kb + (size_t)r * 16 * DD, &wtB[nxt][(w * 8 + r) * 512]);
            k0 = *(const f32x4*)(krow + kb);
            k1 = *(const f32x4*)(krow + kb + 16);
        }
        bf16x8 af[4];
#pragma unroll
        for (int i = 0; i < 4; ++i)
            af[i] = *(const bf16x8*)&ksA[cur][i * 512 + lane * 8];
#pragma unroll
        for (int jn = 0; jn < 8; ++jn) {
            bf16x8 bfr = *(const bf16x8*)&wtB[cur][(w * 8 + jn) * 512 + lane * 8];
#pragma unroll
            for (int i = 0; i < 4; ++i)
                acc[i][jn] = __builtin_amdgcn_mfma_f32_16x16x32_bf16(af[i], bfr, acc[i][jn], 0, 0, 0);
        }
        if (j < 15) {
            cvt_store_bf4(&ksA[nxt][stA0], k0);
            cvt_store_bf4(&ksA[nxt][stA1], k1);
        }
        __syncthreads();
    }

    // epilogue: e-partials.  C layout: row = quad*4 + reg, col = ml
    float qv[8], vv[8];
#pragma unroll
    for (int jn = 0; jn < 8; ++jn) {
        const int n = w * 128 + jn * 16 + ml;
        qv[jn] = qproj[b * DD + n];
        vv[jn] = vvec[n];
    }
#pragma unroll
    for (int i = 0; i < 4; ++i) {
#pragma unroll
        for (int r = 0; r < 4; ++r) {
            float s = 0.0f;
#pragma unroll
            for (int jn = 0; jn < 8; ++jn) {
                float xx = acc[i][jn][r] + qv[jn];
                s += tanh_fast(xx) * vv[jn];
            }
            s += __shfl_xor(s, 1, 64);
            s += __shfl_xor(s, 2, 64);
            s += __shfl_xor(s, 4, 64);
            s += __shfl_xor(s, 8, 64);
            if (ml == 0) sm_part[w][i * 16 + quad * 4 + r] = s;
        }
    }
    __syncthreads();

    // block-local softmax stats (one wave: tid < 64, each thread one s-row)
    if (tid < 64) {
        float e = sm_part[0][tid] + sm_part[1][tid] + sm_part[2][tid] + sm_part[3][tid];
        const int mk = mask[b * SS + s0 + tid];
        if (mk == 0) e = -3.402823466e38f;
        e_ws[(size_t)b * SS + s0 + tid] = e;
        float mx = e;
#pragma unroll
        for (int off = 32; off >= 1; off >>= 1) mx = fmaxf(mx, __shfl_xor(mx, off, 64));
        float wv = (mk == 0) ? 0.0f : __expf(e - mx);
        float l  = wv;
#pragma unroll
        for (int off = 32; off >= 1; off >>= 1) l += __shfl_xor(l, off, 64);
        w_sh[tid] = wv;
        if (tid == 0) ml_ws[b * 128 + chunk] = make_float2(mx, l);
    }
    __syncthreads();

    // context partial: c[n] = sum_{s in 64} w_s * keys[s][n]  (fp32, L2-hot)
    const int n4 = (tid & 127) << 2;
    const int sh = tid >> 7;
    const float* kctx = keys + ((size_t)(b * SS + s0 + sh * 32)) * DD + n4;
    f32x4 cacc = (f32x4){0.f, 0.f, 0.f, 0.f};
#pragma unroll 8
    for (int sI = 0; sI < 32; ++sI) {
        float wgt = w_sh[sh * 32 + sI];
        f32x4 kv  = *(const f32x4*)(kctx + (size_t)sI * DD);
        cacc += kv * wgt;
    }
    if (sh == 1) red[tid & 127] = cacc;
    __syncthreads();
    if (sh == 0) {
        cacc += red[tid];
        *(f32x4*)(cpart + ((size_t)(b * 128 + chunk)) * 512 + n4) = cacc;
    }
}

// ---------------------------------------------------------------------------
// Kernel 3: finalize.
//  blocks 0..15:    c[b][n] = (sum_i cpart[b][i][n]*exp(m_i-M)) / L
//  blocks 16..143:  a[b][s] = exp(e[b][s]-M)/L   (1024 s per block)
// ---------------------------------------------------------------------------
__global__ __launch_bounds__(256) void finalize_kernel(
    const float* __restrict__ e_ws, const float* __restrict__ cpart,
    const float2* __restrict__ ml_ws, float* __restrict__ out)
{
    const int bid = blockIdx.x, t = threadIdx.x;
    const int b = (bid < 16) ? bid : ((bid - 16) >> 3);

    // global M, L over this b's 128 chunk stats
    float mi = -3.402823466e38f, li = 0.0f;
    if (t < 128) { float2 p = ml_ws[b * 128 + t]; mi = p.x; li = p.y; }
    float mr = mi;
#pragma unroll
    for (int off = 32; off >= 1; off >>= 1) mr = fmaxf(mr, __shfl_xor(mr, off, 64));
    __shared__ float rm[4], rs[4];
    if ((t & 63) == 0) rm[t >> 6] = mr;
    __syncthreads();
    const float M = fmaxf(fmaxf(rm[0], rm[1]), fmaxf(rm[2], rm[3]));
    float si = (t < 128) ? li * __expf(mi - M) : 0.0f;
#pragma unroll
    for (int off = 32; off >= 1; off >>= 1) si += __shfl_xor(si, off, 64);
    if ((t & 63) == 0) rs[t >> 6] = si;
    __syncthreads();
    const float L = rs[0] + rs[1] + rs[2] + rs[3];
    const float invL = 1.0f / L;

    if (bid < 16) {
        const int n0 = t * 2;
        float a0 = 0.0f, a1 = 0.0f;
        for (int i = 0; i < 128; ++i) {
            float2 p = ml_ws[b * 128 + i];
            float sc = __expf(p.x - M);
            const float* cp = cpart + ((size_t)(b * 128 + i)) * 512 + n0;
            a0 = fmaf(cp[0], sc, a0);
            a1 = fmaf(cp[1], sc, a1);
        }
        out[b * DD + n0]     = a0 * invL;
        out[b * DD + n0 + 1] = a1 * invL;
    } else {
        const int chunk8 = (bid - 16) & 7;
        const float* ep = e_ws + (size_t)b * SS + chunk8 * 1024;
        float* ap = out + BB * DD + (size_t)b * SS + chunk8 * 1024;
#pragma unroll
        for (int r = 0; r < 4; ++r) {
            float e = ep[t + 256 * r];
            ap[t + 256 * r] = __expf(e - M) * invL;
        }
    }
}

// ---------------------------------------------------------------------------
extern "C" void kernel_launch(void* const* d_in, const int* in_sizes, int n_in,
                              void* d_out, int out_size, void* d_ws, size_t ws_size,
                              hipStream_t stream)
{
    const float* query = (const float*)d_in[0];
    const float* keys  = (const float*)d_in[1];
    const int*   mask  = (const int*)  d_in[2];
    const float* Wq    = (const float*)d_in[3];
    const float* Wk    = (const float*)d_in[4];
    const float* v     = (const float*)d_in[5];
    float* out = (float*)d_out;

    // workspace layout
    float*          qproj = (float*)d_ws;                                     // 32 KB
    unsigned short* WkT   = (unsigned short*)((char*)d_ws + 32768);           // 512 KB
    float*          e_ws  = (float*)((char*)d_ws + 32768 + 524288);           // 512 KB
    float*          cpart = (float*)((char*)d_ws + 32768 + 2 * 524288);       // 4 MB
    float2*         ml_ws = (float2*)((char*)d_ws + 32768 + 2 * 524288 + 4194304); // 16 KB

    prep_kernel    <<<DD + 32, 256, 0, stream>>>(query, Wq, Wk, qproj, WkT);
    fused_kernel   <<<BB * (SS / 64), 256, 0, stream>>>(keys, WkT, qproj, v, mask,
                                                        e_ws, cpart, ml_ws);
    finalize_kernel<<<16 + 128, 256, 0, stream>>>(e_ws, cpart, ml_ws, out);
}